// Round 8
// baseline (851.169 us; speedup 1.0000x reference)
//
#include <hip/hip_runtime.h>
#include <hip/hip_fp16.h>

// ---------------------------------------------------------------------------
// GraphAttention on MI355X (gfx950). f16 MFMA, fp32 accum.
// R8 change vs R7 (isolated): 256x128 block tile, 4 waves (2Mx2N), per-wave
// 128x64 output, acc[8][4]. Raises per-wave arithmetic intensity 16->43
// FLOP/LDS-byte (R7 profile: VALUBusy 41% > MfmaUtil 16.5% => issue-bound).
// Staging/swizzle/2-barrier loop/epilogue primitives unchanged; epilogue runs
// in two 128-row halves through a 32KB Cld alias.
// ---------------------------------------------------------------------------

typedef _Float16 h8 __attribute__((ext_vector_type(8)));
typedef _Float16 h4 __attribute__((ext_vector_type(4)));
typedef float f4 __attribute__((ext_vector_type(4)));

__device__ __forceinline__ void load_lds16(const void* g, void* l) {
  __builtin_amdgcn_global_load_lds(
      (const __attribute__((address_space(1))) unsigned int*)g,
      (__attribute__((address_space(3))) unsigned int*)l, 16, 0, 0);
}

struct GP {
  const _Float16* A; const _Float16* B; void* C; const float* bias;
  const unsigned long long* adjb; _Float16* aux;
  int K, ldA, ldB, ldC, z0, ntx, nty, nz;
  long sAz, sAb, sBz, sBh, sCz, sCb, sCh, sBiasH, sAuxZ;
};

// Stage A (256x64, chunks 0..31) and B (128x64, chunks 32..47) into LDS.
// Element (row,k) lives at byte row*128 + ((2k) ^ ((row&7)<<4)).
__device__ __forceinline__ void stage_tiles2(const _Float16* Ag, const _Float16* Bg,
                                             _Float16* As, _Float16* Bs,
                                             int ldA, int ldB, int wv, int rs, int cs) {
#pragma unroll
  for (int ps = 0; ps < 12; ++ps) {
    int c = ps * 4 + wv;            // 0..47, wave-uniform
    if (c < 32) {
      int r = c * 8 + rs;           // A row 0..255
      int kb = (cs ^ (r & 7)) * 8;
      load_lds16(Ag + (long)r * ldA + kb, As + c * 512);
    } else {
      int cb = c - 32;
      int r = cb * 8 + rs;          // B row 0..127
      int kb = (cs ^ (r & 7)) * 8;
      load_lds16(Bg + (long)r * ldB + kb, Bs + cb * 512);
    }
  }
}

__device__ __forceinline__ void compute_tile2(const _Float16* As, const _Float16* Bs,
                                              f4 acc[8][4], int wr, int wc, int l15, int lg) {
#pragma unroll
  for (int ks = 0; ks < 2; ++ks) {
    const int kby = ks * 64 + lg * 16;
    h8 bv[4];
#pragma unroll
    for (int n = 0; n < 4; ++n) {
      int col = wc * 64 + n * 16 + l15;
      bv[n] = *(const h8*)((const char*)Bs + col * 128 + (kby ^ ((col & 7) << 4)));
    }
#pragma unroll
    for (int m = 0; m < 8; ++m) {
      int row = wr * 128 + m * 16 + l15;
      h8 av = *(const h8*)((const char*)As + row * 128 + (kby ^ ((row & 7) << 4)));
#pragma unroll
      for (int n = 0; n < 4; ++n)
        acc[m][n] = __builtin_amdgcn_mfma_f32_16x16x32_f16(av, bv[n], acc[m][n], 0, 0, 0);
    }
  }
}

// BT-GEMM body: C[M,N] = A[M,K]*B[N,K]^T, 256x128 tile, BK=64, 4 waves,
// single-buffered 48KB LDS, 1D XCD-aware grid, f16-LDS epilogue in 2 halves.
// EPI: 0 f16 | 2 mask+tanh f16 | 3 relu f16 | 5 bias+sigmoid f16 (coeff)
//      | 6 bias f16 + dual store (C and aux=C^T)
template<int EPI>
__device__ __forceinline__ void gemm_core(GP p) {
  __shared__ __align__(16) char smem[49152];
  _Float16* Ash = (_Float16*)smem;                    // [256*64] f16, 32KB
  _Float16* Bsh = (_Float16*)(smem + 32768);          // [128*64] f16, 16KB
  _Float16* Cld = (_Float16*)smem;                    // epilogue alias, 32KB

  const int tid = threadIdx.x;
  const int wv = tid >> 6;
  const int ln = tid & 63;
  const int l15 = ln & 15;
  const int lg = ln >> 4;
  const int wr = wv >> 1, wc = wv & 1;   // 2M x 2N wave grid
  const int rs = ln >> 3;
  const int cs = ln & 7;

  // --- block decode: XCD-aware ---
  const int bid = blockIdx.x;
  const int ntile = p.ntx * p.nty;
  int zl, tx, ty;
  if (p.nz > 1) {
    // all tiles of one z pinned to xcd = z&7  (nz % 8 == 0, bijective)
    int xcd = bid & 7;
    int u = bid >> 3;
    zl = xcd + 8 * (u / ntile);
    int t = u % ntile;
    tx = t % p.ntx;
    ty = t / p.ntx;
  } else {
    // bijective chunked swizzle (ntile % 8 == 0)
    int xcd = bid & 7;
    int u = bid >> 3;
    int t = xcd * (ntile >> 3) + u;
    zl = 0;
    tx = t % p.ntx;
    ty = t / p.ntx;
  }
  const int zg = p.z0 + zl;
  const int bg = zg >> 2, hg = zg & 3;  // H=4
  const _Float16* A = p.A + p.sAz * zl + p.sAb * bg;
  const _Float16* Bm = p.B + p.sBz * zl + p.sBh * hg;
  const long m0 = (long)tx * 256;
  const long n0 = (long)ty * 128;
  const int nk = p.K >> 6;

  f4 acc[8][4];
#pragma unroll
  for (int i = 0; i < 8; ++i)
#pragma unroll
    for (int j = 0; j < 4; ++j) acc[i][j] = (f4)(0.0f);

  const _Float16* Ag = A + m0 * p.ldA;
  const _Float16* Bg = Bm + n0 * p.ldB;

  // --- main loop: single buffer, 2 barriers per K-step ---
  for (int kt = 0; kt < nk; ++kt) {
    stage_tiles2(Ag + kt * 64, Bg + kt * 64, Ash, Bsh, p.ldA, p.ldB, wv, rs, cs);
    __syncthreads();
    compute_tile2(Ash, Bsh, acc, wr, wc, l15, lg);
    __syncthreads();
  }

  // --- epilogue: two 128-row halves through 32KB Cld ---
  const long coff = p.sCz * zl + p.sCb * bg + p.sCh * hg;
  const float* bias = p.bias ? (p.bias + p.sBiasH * hg) : nullptr;
  _Float16* C = (_Float16*)p.C;
  _Float16* X = (EPI == 6) ? (p.aux + p.sAuxZ * zl) : nullptr;
#pragma unroll
  for (int hf2 = 0; hf2 < 2; ++hf2) {
    __syncthreads();   // Cld (alias of Ash) free: main-loop / prev-half reads done
    if (wr == hf2) {   // waves owning M-rows [hf2*128, hf2*128+128)
#pragma unroll
      for (int m = 0; m < 8; ++m) {
#pragma unroll
        for (int j = 0; j < 4; ++j) {
          int lrow = m * 16 + lg * 4 + j;          // 0..127 within half
          long grow = m0 + hf2 * 128 + lrow;
          int vx = (lrow & 12) << 2;
          unsigned long long w;
          if (EPI == 2)  // wave-uniform 64-col word (cols n0+wc*64 .. +63)
            w = p.adjb[(long)bg * 16384 + grow * 16 + (n0 >> 6) + wc];
#pragma unroll
          for (int n = 0; n < 4; ++n) {
            int lcol = wc * 64 + n * 16 + l15;
            float v = acc[m][n][j];
            if (EPI == 5 || EPI == 6) v += bias[n0 + lcol];
            if (EPI == 2) {
              if ((w >> (n * 16 + l15)) & 1ull) {
                float ex = __expf(2.0f * v);                   // tanh = 1-2/(e^2x+1)
                v = 1.0f - 2.0f * __builtin_amdgcn_rcpf(ex + 1.0f);
              } else v = 0.0f;
            }
            if (EPI == 3) v = v > 0.0f ? v : 0.0f;
            if (EPI == 5) v = __builtin_amdgcn_rcpf(1.0f + __expf(-v));  // sigmoid
            Cld[lrow * 128 + (lcol ^ vx)] = (_Float16)v;
          }
        }
      }
    }
    __syncthreads();
    // store phase: all 256 threads, 128x128 f16
#pragma unroll
    for (int it = 0; it < 8; ++it) {
      int row = it * 16 + (tid >> 4);
      int col0 = (tid & 15) * 8;
      int vx = (row & 12) << 2;
      h8 o = *(const h8*)&Cld[row * 128 + (col0 ^ vx)];
      *(h8*)&C[coff + (m0 + hf2 * 128 + row) * p.ldC + n0 + col0] = o;
    }
    if (EPI == 6) {
      // dual store: aux[col][row] = C-tile^T  (WhT [512][1024] per z)
#pragma unroll
      for (int pass = 0; pass < 8; ++pass) {
        int ol = pass * 16 + (tid >> 4);   // 0..127 (tile col)
        int ml = (tid & 15) * 8;           // row block within half
        h8 o;
#pragma unroll
        for (int j = 0; j < 8; ++j) {
          int mm = ml + j;
          o[j] = Cld[mm * 128 + (ol ^ ((mm & 12) << 2))];
        }
        *(h8*)&X[(n0 + ol) * 1024 + m0 + hf2 * 128 + ml] = o;
      }
    }
  }
}

#define GEMM_WRAP(name, epi) \
  __global__ __launch_bounds__(256) void name(GP p) { gemm_core<epi>(p); }
GEMM_WRAP(gemm_wh, 6)
GEMM_WRAP(gemm_e, 0)
GEMM_WRAP(gemm_amat, 2)
GEMM_WRAP(gemm_cat, 3)
GEMM_WRAP(gemm_hf, 0)
GEMM_WRAP(gemm_ha, 0)
GEMM_WRAP(gemm_gate, 5)

// out = hf*cf + ha*(1-cf); streaming, grid-stride, high TLP
__global__ __launch_bounds__(256) void mix_kernel(const _Float16* gcat,
                                                  const _Float16* coeff, float* out) {
  const int stride = gridDim.x * 256;
  for (int g = blockIdx.x * 256 + threadIdx.x; g < 1048576; g += stride) {
    int r = g >> 6, c8 = (g & 63) << 3;
    h8 hf = *(const h8*)&gcat[(long)r * 1024 + c8];
    h8 ha = *(const h8*)&gcat[(long)r * 1024 + 512 + c8];
    h8 cf = *(const h8*)&coeff[(long)r * 512 + c8];
    float o[8];
#pragma unroll
    for (int j = 0; j < 8; ++j) {
      float c = (float)cf[j];
      o[j] = (float)hf[j] * c + (float)ha[j] * (1.0f - c);
    }
    float* op = &out[(long)r * 512 + c8];
    *(float4*)op = make_float4(o[0], o[1], o[2], o[3]);
    *(float4*)(op + 4) = make_float4(o[4], o[5], o[6], o[7]);
  }
}

// attn [h][o][p] fp32 -> attnT [h][p][o] f16
__global__ void trans_attn(const float* attn, _Float16* attnT) {
  __shared__ _Float16 tl[64][65];
  const long hh = blockIdx.z;
  const float* I = attn + hh * 262144;
  _Float16* O = attnT + hh * 262144;
  const int r0 = blockIdx.x * 64, c0 = blockIdx.y * 64;
  for (int i = threadIdx.x; i < 4096; i += 256) {
    int r = i >> 6, c = i & 63;
    tl[c][r] = (_Float16)I[(long)(r0 + r) * 512 + c0 + c];
  }
  __syncthreads();
  for (int i = threadIdx.x; i < 4096; i += 256) {
    int c = i >> 6, r = i & 63;
    O[(long)(c0 + c) * 512 + r0 + r] = tl[c][r];
  }
}

__global__ void cvt_f16(const float* in, _Float16* out, int n4) {
  int i = blockIdx.x * 256 + threadIdx.x;
  if (i < n4) {
    float4 v = ((const float4*)in)[i];
    h4 o = {(_Float16)v.x, (_Float16)v.y, (_Float16)v.z, (_Float16)v.w};
    ((h4*)out)[i] = o;
  }
}

__global__ void build_gw(const float* g1, const float* g2, _Float16* gw) {
  int i = blockIdx.x * 256 + threadIdx.x;  // 524288
  int o = i >> 10, k = i & 1023;
  float v = (k < 512) ? g1[o * 512 + k] : g2[o * 512 + (k - 512)];
  gw[i] = (_Float16)v;
}

// Probe adj element format. fmt: 0=int32, 1=byte/bool, 2=int64, 3=float32
__global__ void detect_fmt(const unsigned char* adj, int* flags) {
  __shared__ int sa, sb, sc;
  if (threadIdx.x == 0) { sa = 0; sb = 0; sc = 0; }
  __syncthreads();
  int a = 0, b = 0, c = 0;
  for (int i = threadIdx.x; i < 4096; i += 256) {
    if (adj[i]) {
      if (i & 3) a = 1;
      else c = 1;
      if ((i & 7) == 4) b = 1;
    }
  }
  if (a) sa = 1;
  if (b) sb = 1;
  if (c) sc = 1;
  __syncthreads();
  if (threadIdx.x == 0) {
    int fmt;
    if (sa) fmt = sc ? 1 : 3;
    else fmt = sb ? 0 : 2;
    flags[0] = fmt;
  }
}

__global__ void adj_bits(const void* adj, const int* flags, unsigned long long* adjb) {
  long i = (long)blockIdx.x * 256 + threadIdx.x;  // 16,777,216 elements
  int fmt = flags[0];
  bool v;
  if (fmt == 1) v = ((const unsigned char*)adj)[i] != 0;
  else if (fmt == 3) v = ((const float*)adj)[i] != 0.0f;
  else if (fmt == 2) v = ((const long long*)adj)[i] != 0;
  else v = ((const int*)adj)[i] != 0;
  unsigned long long m = __ballot(v);
  if ((threadIdx.x & 63) == 0) adjb[i >> 6] = m;
}

extern "C" void kernel_launch(void* const* d_in, const int* in_sizes, int n_in,
                              void* d_out, int out_size, void* d_ws, size_t ws_size,
                              hipStream_t stream) {
  const float* h    = (const float*)d_in[0];
  const void*  adj  = d_in[1];
  const float* W    = (const float*)d_in[2];
  const float* bW   = (const float*)d_in[3];
  const float* attn = (const float*)d_in[4];
  const float* A_w  = (const float*)d_in[5];
  const float* fc_w = (const float*)d_in[6];
  const float* g1   = (const float*)d_in[7];
  const float* g2   = (const float*)d_in[8];
  const float* gbias= (const float*)d_in[9];
  float* out = (float*)d_out;
  char* ws = (char*)d_ws;
  (void)in_sizes; (void)n_in; (void)out_size;

  // --- exact-fit chunk sizing ---
  const size_t MB = 1ull << 20;
  const size_t fixedB = 92 * MB;           // fixed buffers (~89.8MB) + slack
  int ZCv = 16;
  if (fixedB + 5ull * 64 * MB <= ws_size) ZCv = 64;
  else if (fixedB + 5ull * 32 * MB <= ws_size) ZCv = 32;
  const int nchunk = 64 / ZCv;

  size_t off = 0;
  auto alloc = [&](size_t sz) { size_t o = off; off += (sz + 255) & ~(size_t)255; return o; };
  const size_t oFlags = alloc(256);
  const size_t oH16   = alloc(16 * MB);
  const size_t oW16   = alloc(2 * MB);
  const size_t oAttnT = alloc(2 * MB);
  const size_t oAw16  = alloc(2 * MB);
  const size_t oFc16  = alloc(512 * 1024);
  const size_t oGw16  = alloc(1 * MB);
  const size_t oAdjb  = alloc(2 * MB);
  const size_t oCat   = alloc(64 * MB);
  const size_t oWhC   = alloc((size_t)ZCv * MB);       // Wh chunk f16 [ZC][1024][512]
  const size_t oEC    = alloc((size_t)ZCv * MB);       // e chunk (contiguous after WhC)
  const size_t oWhTC  = alloc((size_t)ZCv * MB);       // WhT chunk f16 [ZC][512][1024]
  const size_t oAmatC = alloc((size_t)ZCv * 2 * MB);   // Amat chunk f16 [ZC][1024][1024]
  const size_t oGcat  = oWhC;    // gcat f16 [16384][1024] (32MB <= WhC+EC)
  const size_t oCoeff = oAmatC;  // coeff f16 [16384][512] (16MB <= AmatC)

  int* flags = (int*)(ws + oFlags);
  _Float16* h16   = (_Float16*)(ws + oH16);
  _Float16* W16   = (_Float16*)(ws + oW16);
  _Float16* attnT = (_Float16*)(ws + oAttnT);
  _Float16* Aw16  = (_Float16*)(ws + oAw16);
  _Float16* fc16  = (_Float16*)(ws + oFc16);
  _Float16* gw16  = (_Float16*)(ws + oGw16);
  unsigned long long* adjb = (unsigned long long*)(ws + oAdjb);
  _Float16* cat   = (_Float16*)(ws + oCat);
  _Float16* WhC   = (_Float16*)(ws + oWhC);
  _Float16* eC    = (_Float16*)(ws + oEC);
  _Float16* WhTC  = (_Float16*)(ws + oWhTC);
  _Float16* AmatC = (_Float16*)(ws + oAmatC);
  _Float16* gcat  = (_Float16*)(ws + oGcat);
  _Float16* coeff = (_Float16*)(ws + oCoeff);

  // --- prep ---
  detect_fmt<<<1, 256, 0, stream>>>((const unsigned char*)adj, flags);
  adj_bits<<<65536, 256, 0, stream>>>(adj, flags, adjb);
  cvt_f16<<<8192, 256, 0, stream>>>(h, h16, 2097152);
  cvt_f16<<<1024, 256, 0, stream>>>(W, W16, 262144);
  cvt_f16<<<1024, 256, 0, stream>>>(A_w, Aw16, 262144);
  cvt_f16<<<256, 256, 0, stream>>>(fc_w, fc16, 65536);
  build_gw<<<2048, 256, 0, stream>>>(g1, g2, gw16);
  trans_attn<<<dim3(8, 8, 4), 256, 0, stream>>>(attn, attnT);

  // --- heavy pipeline (per chunk) ---
  for (int c = 0; c < nchunk; ++c) {
    const int z0 = c * ZCv;
    GP q;
    // Wh = h*W^T + bW  (+ WhT dual store)
    q = GP{};
    q.A = h16; q.B = W16; q.C = WhC; q.bias = bW; q.aux = WhTC;
    q.K = 512; q.ldA = 512; q.ldB = 512; q.ldC = 512; q.z0 = z0;
    q.ntx = 4; q.nty = 4; q.nz = ZCv;
    q.sAz = 0; q.sAb = 524288; q.sBz = 0; q.sBh = 262144;
    q.sCz = 524288; q.sCb = 0; q.sCh = 0; q.sBiasH = 512; q.sAuxZ = 524288;
    gemm_wh<<<16 * ZCv, 256, 0, stream>>>(q);
    // e = Wh*attn
    q = GP{};
    q.A = WhC; q.B = attnT; q.C = eC;
    q.K = 512; q.ldA = 512; q.ldB = 512; q.ldC = 512; q.z0 = z0;
    q.ntx = 4; q.nty = 4; q.nz = ZCv;
    q.sAz = 524288; q.sBh = 262144; q.sCz = 524288;
    gemm_e<<<16 * ZCv, 256, 0, stream>>>(q);
    // Amat = tanh(mask(e*Wh^T))
    q = GP{};
    q.A = eC; q.B = WhC; q.C = AmatC; q.adjb = adjb;
    q.K = 512; q.ldA = 512; q.ldB = 512; q.ldC = 1024; q.z0 = z0;
    q.ntx = 4; q.nty = 8; q.nz = ZCv;
    q.sAz = 524288; q.sBz = 524288; q.sCz = 1048576;
    gemm_amat<<<32 * ZCv, 256, 0, stream>>>(q);
    // cat[b][n][h*512+o] = relu(Amat*WhT^T)
    q = GP{};
    q.A = AmatC; q.B = WhTC; q.C = cat;
    q.K = 1024; q.ldA = 1024; q.ldB = 1024; q.ldC = 2048; q.z0 = z0;
    q.sAz = 1048576; q.sBz = 524288;
    q.ntx = 4; q.nty = 4; q.nz = ZCv;
    q.sCz = 0; q.sCb = 2097152; q.sCh = 512;
    gemm_cat<<<16 * ZCv, 256, 0, stream>>>(q);
  }

  // --- tail ---
  GP q;
  // hf = h*fc^T -> gcat[:,0:512]
  q = GP{};
  q.A = h16; q.B = fc16; q.C = gcat;
  q.K = 512; q.ldA = 512; q.ldB = 512; q.ldC = 1024; q.z0 = 0;
  q.ntx = 64; q.nty = 4; q.nz = 1;
  gemm_hf<<<256, 256, 0, stream>>>(q);
  // ha = cat*A_w^T -> gcat[:,512:1024]
  q = GP{};
  q.A = cat; q.B = Aw16; q.C = gcat + 512;
  q.K = 2048; q.ldA = 2048; q.ldB = 2048; q.ldC = 1024; q.z0 = 0;
  q.ntx = 64; q.nty = 4; q.nz = 1;
  gemm_ha<<<256, 256, 0, stream>>>(q);
  // coeff = sigmoid(gcat*[g1|g2]^T + gbias)
  q = GP{};
  q.A = gcat; q.B = gw16; q.C = coeff; q.bias = gbias;
  q.K = 1024; q.ldA = 1024; q.ldB = 1024; q.ldC = 512; q.z0 = 0;
  q.ntx = 64; q.nty = 4; q.nz = 1; q.sBiasH = 0;
  gemm_gate<<<256, 256, 0, stream>>>(q);
  // out = hf*cf + ha*(1-cf)
  mix_kernel<<<2048, 256, 0, stream>>>(gcat, coeff, out);
}

// Round 9
// 492.280 us; speedup vs baseline: 1.7290x; 1.7290x over previous
//
#include <hip/hip_runtime.h>
#include <hip/hip_fp16.h>

// ---------------------------------------------------------------------------
// GraphAttention on MI355X (gfx950). f16 MFMA, fp32 accum.
// R9 change vs R8: revert to R7 per-wave geometry (64x64 out, acc[4][4]),
// but 128x256 block tile with 8 waves (512 thr). Waves/CU is the proven
// controlling variable (R7 6.4 waves->414TF, R8 4 waves->234TF): 48KB LDS
// + ~120 regs => 2 blocks x 8 waves = 16 waves/CU (~2.5x R7). Sync structure
// (single-buffer, 2 barriers/K-step), swizzles, epilogues unchanged.
// ---------------------------------------------------------------------------

typedef _Float16 h8 __attribute__((ext_vector_type(8)));
typedef _Float16 h4 __attribute__((ext_vector_type(4)));
typedef float f4 __attribute__((ext_vector_type(4)));

__device__ __forceinline__ void load_lds16(const void* g, void* l) {
  __builtin_amdgcn_global_load_lds(
      (const __attribute__((address_space(1))) unsigned int*)g,
      (__attribute__((address_space(3))) unsigned int*)l, 16, 0, 0);
}

struct GP {
  const _Float16* A; const _Float16* B; void* C; const float* bias;
  const unsigned long long* adjb; _Float16* aux;
  int K, ldA, ldB, ldC, z0, ntx, nty, nz;
  long sAz, sAb, sBz, sBh, sCz, sCb, sCh, sBiasH, sAuxZ;
};

// Stage A (128x64, chunks 0..15) and B (256x64, chunks 16..47) into LDS.
// Element (row,k) lives at byte row*128 + ((2k) ^ ((row&7)<<4)).
// Each wave issues exactly 6 global_load_lds.
__device__ __forceinline__ void stage_tiles3(const _Float16* Ag, const _Float16* Bg,
                                             _Float16* As, _Float16* Bs,
                                             int ldA, int ldB, int wv, int rs, int cs) {
#pragma unroll
  for (int ps = 0; ps < 6; ++ps) {
    int c = ps * 8 + wv;            // 0..47, wave-uniform
    if (c < 16) {
      int r = c * 8 + rs;           // A row 0..127
      int kb = (cs ^ (r & 7)) * 8;
      load_lds16(Ag + (long)r * ldA + kb, As + c * 512);
    } else {
      int cb = c - 16;
      int r = cb * 8 + rs;          // B row 0..255
      int kb = (cs ^ (r & 7)) * 8;
      load_lds16(Bg + (long)r * ldB + kb, Bs + cb * 512);
    }
  }
}

__device__ __forceinline__ void compute_tile3(const _Float16* As, const _Float16* Bs,
                                              f4 acc[4][4], int wr, int wc, int l15, int lg) {
#pragma unroll
  for (int ks = 0; ks < 2; ++ks) {
    const int kby = ks * 64 + lg * 16;
    h8 av[4], bv[4];
#pragma unroll
    for (int m = 0; m < 4; ++m) {
      int row = wr * 64 + m * 16 + l15;
      av[m] = *(const h8*)((const char*)As + row * 128 + (kby ^ ((row & 7) << 4)));
    }
#pragma unroll
    for (int n = 0; n < 4; ++n) {
      int col = wc * 64 + n * 16 + l15;
      bv[n] = *(const h8*)((const char*)Bs + col * 128 + (kby ^ ((col & 7) << 4)));
    }
#pragma unroll
    for (int m = 0; m < 4; ++m)
#pragma unroll
      for (int n = 0; n < 4; ++n)
        acc[m][n] = __builtin_amdgcn_mfma_f32_16x16x32_f16(av[m], bv[n], acc[m][n], 0, 0, 0);
  }
}

// BT-GEMM body: C[M,N] = A[M,K]*B[N,K]^T, 128x256 tile, BK=64, 8 waves
// (2M x 4N, per-wave 64x64), single-buffered 48KB LDS, 1D XCD-aware grid,
// f16-LDS epilogue in two 128-col halves.
// EPI: 0 f16 | 2 mask+tanh f16 | 3 relu f16 | 5 bias+sigmoid f16 (coeff)
//      | 6 bias f16 + dual store (C and aux=C^T)
template<int EPI>
__device__ __forceinline__ void gemm_core(GP p) {
  __shared__ __align__(16) char smem[49152];
  _Float16* Ash = (_Float16*)smem;                    // [128*64] f16, 16KB
  _Float16* Bsh = (_Float16*)(smem + 16384);          // [256*64] f16, 32KB
  _Float16* Cld = (_Float16*)smem;                    // epilogue alias, 32KB

  const int tid = threadIdx.x;
  const int wv = tid >> 6;
  const int ln = tid & 63;
  const int l15 = ln & 15;
  const int lg = ln >> 4;
  const int wr = wv >> 2, wc = wv & 3;   // 2M x 4N wave grid
  const int rs = ln >> 3;
  const int cs = ln & 7;

  // --- block decode: XCD-aware ---
  const int bid = blockIdx.x;
  const int ntile = p.ntx * p.nty;
  int zl, tx, ty;
  if (p.nz > 1) {
    // all tiles of one z pinned to xcd = z&7  (nz % 8 == 0, bijective)
    int xcd = bid & 7;
    int u = bid >> 3;
    zl = xcd + 8 * (u / ntile);
    int t = u % ntile;
    tx = t % p.ntx;
    ty = t / p.ntx;
  } else {
    // bijective chunked swizzle (ntile % 8 == 0)
    int xcd = bid & 7;
    int u = bid >> 3;
    int t = xcd * (ntile >> 3) + u;
    zl = 0;
    tx = t % p.ntx;
    ty = t / p.ntx;
  }
  const int zg = p.z0 + zl;
  const int bg = zg >> 2, hg = zg & 3;  // H=4
  const _Float16* A = p.A + p.sAz * zl + p.sAb * bg;
  const _Float16* Bm = p.B + p.sBz * zl + p.sBh * hg;
  const long m0 = (long)tx * 128;
  const long n0 = (long)ty * 256;
  const int nk = p.K >> 6;

  f4 acc[4][4];
#pragma unroll
  for (int i = 0; i < 4; ++i)
#pragma unroll
    for (int j = 0; j < 4; ++j) acc[i][j] = (f4)(0.0f);

  const _Float16* Ag = A + m0 * p.ldA;
  const _Float16* Bg = Bm + n0 * p.ldB;

  // --- main loop: single buffer, 2 barriers per K-step (R7-proven) ---
  for (int kt = 0; kt < nk; ++kt) {
    stage_tiles3(Ag + kt * 64, Bg + kt * 64, Ash, Bsh, p.ldA, p.ldB, wv, rs, cs);
    __syncthreads();
    compute_tile3(Ash, Bsh, acc, wr, wc, l15, lg);
    __syncthreads();
  }

  // --- epilogue: two 128-col halves through 32KB Cld ---
  const long coff = p.sCz * zl + p.sCb * bg + p.sCh * hg;
  const float* bias = p.bias ? (p.bias + p.sBiasH * hg) : nullptr;
  _Float16* C = (_Float16*)p.C;
  _Float16* X = (EPI == 6) ? (p.aux + p.sAuxZ * zl) : nullptr;
#pragma unroll
  for (int ch = 0; ch < 2; ++ch) {
    __syncthreads();   // Cld (alias of Ash/Bsh) free for this half
    if ((wc >> 1) == ch) {   // 4 waves own cols [ch*128, ch*128+128)
#pragma unroll
      for (int m = 0; m < 4; ++m) {
#pragma unroll
        for (int j = 0; j < 4; ++j) {
          int lrow = wr * 64 + m * 16 + lg * 4 + j;   // 0..127
          long grow = m0 + lrow;
          int vx = (lrow & 12) << 2;
          unsigned long long w;
          if (EPI == 2)  // wave-uniform 64-col word (cols n0+wc*64 .. +63)
            w = p.adjb[(long)bg * 16384 + grow * 16 + (n0 >> 6) + wc];
#pragma unroll
          for (int n = 0; n < 4; ++n) {
            int lcol = (wc & 1) * 64 + n * 16 + l15;   // col within half
            float v = acc[m][n][j];
            if (EPI == 5 || EPI == 6) v += bias[n0 + wc * 64 + n * 16 + l15];
            if (EPI == 2) {
              if ((w >> (n * 16 + l15)) & 1ull) {
                float ex = __expf(2.0f * v);                   // tanh = 1-2/(e^2x+1)
                v = 1.0f - 2.0f * __builtin_amdgcn_rcpf(ex + 1.0f);
              } else v = 0.0f;
            }
            if (EPI == 3) v = v > 0.0f ? v : 0.0f;
            if (EPI == 5) v = __builtin_amdgcn_rcpf(1.0f + __expf(-v));  // sigmoid
            Cld[lrow * 128 + (lcol ^ vx)] = (_Float16)v;
          }
        }
      }
    }
    __syncthreads();
    // store phase: all 512 threads, 128x128 f16 half-tile
#pragma unroll
    for (int it = 0; it < 4; ++it) {
      int idx = it * 512 + tid;
      int row = idx >> 4;                 // 0..127
      int col0 = (idx & 15) * 8;
      h8 o = *(const h8*)&Cld[row * 128 + (col0 ^ ((row & 12) << 2))];
      *(h8*)&C[coff + (m0 + row) * p.ldC + n0 + ch * 128 + col0] = o;
    }
    if (EPI == 6) {
      // dual store: aux[col][row] = C-tile^T  (WhT [512][1024] per z)
#pragma unroll
      for (int it = 0; it < 4; ++it) {
        int idx = it * 512 + tid;
        int ol = idx >> 4;                // 0..127 (tile col within half)
        int ml = (idx & 15) * 8;          // tile row block
        h8 o;
#pragma unroll
        for (int j = 0; j < 8; ++j) {
          int mm = ml + j;
          o[j] = Cld[mm * 128 + (ol ^ ((mm & 12) << 2))];
        }
        *(h8*)&X[(n0 + ch * 128 + ol) * 1024 + m0 + ml] = o;
      }
    }
  }
}

#define GEMM_WRAP(name, epi) \
  __global__ __launch_bounds__(512) void name(GP p) { gemm_core<epi>(p); }
GEMM_WRAP(gemm_wh, 6)
GEMM_WRAP(gemm_e, 0)
GEMM_WRAP(gemm_amat, 2)
GEMM_WRAP(gemm_cat, 3)
GEMM_WRAP(gemm_hf, 0)
GEMM_WRAP(gemm_ha, 0)
GEMM_WRAP(gemm_gate, 5)

// out = hf*cf + ha*(1-cf); streaming, grid-stride, high TLP
__global__ __launch_bounds__(256) void mix_kernel(const _Float16* gcat,
                                                  const _Float16* coeff, float* out) {
  const int stride = gridDim.x * 256;
  for (int g = blockIdx.x * 256 + threadIdx.x; g < 1048576; g += stride) {
    int r = g >> 6, c8 = (g & 63) << 3;
    h8 hf = *(const h8*)&gcat[(long)r * 1024 + c8];
    h8 ha = *(const h8*)&gcat[(long)r * 1024 + 512 + c8];
    h8 cf = *(const h8*)&coeff[(long)r * 512 + c8];
    float o[8];
#pragma unroll
    for (int j = 0; j < 8; ++j) {
      float c = (float)cf[j];
      o[j] = (float)hf[j] * c + (float)ha[j] * (1.0f - c);
    }
    float* op = &out[(long)r * 512 + c8];
    *(float4*)op = make_float4(o[0], o[1], o[2], o[3]);
    *(float4*)(op + 4) = make_float4(o[4], o[5], o[6], o[7]);
  }
}

// attn [h][o][p] fp32 -> attnT [h][p][o] f16
__global__ void trans_attn(const float* attn, _Float16* attnT) {
  __shared__ _Float16 tl[64][65];
  const long hh = blockIdx.z;
  const float* I = attn + hh * 262144;
  _Float16* O = attnT + hh * 262144;
  const int r0 = blockIdx.x * 64, c0 = blockIdx.y * 64;
  for (int i = threadIdx.x; i < 4096; i += 256) {
    int r = i >> 6, c = i & 63;
    tl[c][r] = (_Float16)I[(long)(r0 + r) * 512 + c0 + c];
  }
  __syncthreads();
  for (int i = threadIdx.x; i < 4096; i += 256) {
    int c = i >> 6, r = i & 63;
    O[(long)(c0 + c) * 512 + r0 + r] = tl[c][r];
  }
}

__global__ void cvt_f16(const float* in, _Float16* out, int n4) {
  int i = blockIdx.x * 256 + threadIdx.x;
  if (i < n4) {
    float4 v = ((const float4*)in)[i];
    h4 o = {(_Float16)v.x, (_Float16)v.y, (_Float16)v.z, (_Float16)v.w};
    ((h4*)out)[i] = o;
  }
}

__global__ void build_gw(const float* g1, const float* g2, _Float16* gw) {
  int i = blockIdx.x * 256 + threadIdx.x;  // 524288
  int o = i >> 10, k = i & 1023;
  float v = (k < 512) ? g1[o * 512 + k] : g2[o * 512 + (k - 512)];
  gw[i] = (_Float16)v;
}

// Probe adj element format. fmt: 0=int32, 1=byte/bool, 2=int64, 3=float32
__global__ void detect_fmt(const unsigned char* adj, int* flags) {
  __shared__ int sa, sb, sc;
  if (threadIdx.x == 0) { sa = 0; sb = 0; sc = 0; }
  __syncthreads();
  int a = 0, b = 0, c = 0;
  for (int i = threadIdx.x; i < 4096; i += 256) {
    if (adj[i]) {
      if (i & 3) a = 1;
      else c = 1;
      if ((i & 7) == 4) b = 1;
    }
  }
  if (a) sa = 1;
  if (b) sb = 1;
  if (c) sc = 1;
  __syncthreads();
  if (threadIdx.x == 0) {
    int fmt;
    if (sa) fmt = sc ? 1 : 3;
    else fmt = sb ? 0 : 2;
    flags[0] = fmt;
  }
}

__global__ void adj_bits(const void* adj, const int* flags, unsigned long long* adjb) {
  long i = (long)blockIdx.x * 256 + threadIdx.x;  // 16,777,216 elements
  int fmt = flags[0];
  bool v;
  if (fmt == 1) v = ((const unsigned char*)adj)[i] != 0;
  else if (fmt == 3) v = ((const float*)adj)[i] != 0.0f;
  else if (fmt == 2) v = ((const long long*)adj)[i] != 0;
  else v = ((const int*)adj)[i] != 0;
  unsigned long long m = __ballot(v);
  if ((threadIdx.x & 63) == 0) adjb[i >> 6] = m;
}

extern "C" void kernel_launch(void* const* d_in, const int* in_sizes, int n_in,
                              void* d_out, int out_size, void* d_ws, size_t ws_size,
                              hipStream_t stream) {
  const float* h    = (const float*)d_in[0];
  const void*  adj  = d_in[1];
  const float* W    = (const float*)d_in[2];
  const float* bW   = (const float*)d_in[3];
  const float* attn = (const float*)d_in[4];
  const float* A_w  = (const float*)d_in[5];
  const float* fc_w = (const float*)d_in[6];
  const float* g1   = (const float*)d_in[7];
  const float* g2   = (const float*)d_in[8];
  const float* gbias= (const float*)d_in[9];
  float* out = (float*)d_out;
  char* ws = (char*)d_ws;
  (void)in_sizes; (void)n_in; (void)out_size;

  // --- exact-fit chunk sizing ---
  const size_t MB = 1ull << 20;
  const size_t fixedB = 92 * MB;           // fixed buffers (~89.8MB) + slack
  int ZCv = 16;
  if (fixedB + 5ull * 64 * MB <= ws_size) ZCv = 64;
  else if (fixedB + 5ull * 32 * MB <= ws_size) ZCv = 32;
  const int nchunk = 64 / ZCv;

  size_t off = 0;
  auto alloc = [&](size_t sz) { size_t o = off; off += (sz + 255) & ~(size_t)255; return o; };
  const size_t oFlags = alloc(256);
  const size_t oH16   = alloc(16 * MB);
  const size_t oW16   = alloc(2 * MB);
  const size_t oAttnT = alloc(2 * MB);
  const size_t oAw16  = alloc(2 * MB);
  const size_t oFc16  = alloc(512 * 1024);
  const size_t oGw16  = alloc(1 * MB);
  const size_t oAdjb  = alloc(2 * MB);
  const size_t oCat   = alloc(64 * MB);
  const size_t oWhC   = alloc((size_t)ZCv * MB);       // Wh chunk f16 [ZC][1024][512]
  const size_t oEC    = alloc((size_t)ZCv * MB);       // e chunk (contiguous after WhC)
  const size_t oWhTC  = alloc((size_t)ZCv * MB);       // WhT chunk f16 [ZC][512][1024]
  const size_t oAmatC = alloc((size_t)ZCv * 2 * MB);   // Amat chunk f16 [ZC][1024][1024]
  const size_t oGcat  = oWhC;    // gcat f16 [16384][1024] (32MB <= WhC+EC)
  const size_t oCoeff = oAmatC;  // coeff f16 [16384][512] (16MB <= AmatC)

  int* flags = (int*)(ws + oFlags);
  _Float16* h16   = (_Float16*)(ws + oH16);
  _Float16* W16   = (_Float16*)(ws + oW16);
  _Float16* attnT = (_Float16*)(ws + oAttnT);
  _Float16* Aw16  = (_Float16*)(ws + oAw16);
  _Float16* fc16  = (_Float16*)(ws + oFc16);
  _Float16* gw16  = (_Float16*)(ws + oGw16);
  unsigned long long* adjb = (unsigned long long*)(ws + oAdjb);
  _Float16* cat   = (_Float16*)(ws + oCat);
  _Float16* WhC   = (_Float16*)(ws + oWhC);
  _Float16* eC    = (_Float16*)(ws + oEC);
  _Float16* WhTC  = (_Float16*)(ws + oWhTC);
  _Float16* AmatC = (_Float16*)(ws + oAmatC);
  _Float16* gcat  = (_Float16*)(ws + oGcat);
  _Float16* coeff = (_Float16*)(ws + oCoeff);

  // --- prep ---
  detect_fmt<<<1, 256, 0, stream>>>((const unsigned char*)adj, flags);
  adj_bits<<<65536, 256, 0, stream>>>(adj, flags, adjb);
  cvt_f16<<<8192, 256, 0, stream>>>(h, h16, 2097152);
  cvt_f16<<<1024, 256, 0, stream>>>(W, W16, 262144);
  cvt_f16<<<1024, 256, 0, stream>>>(A_w, Aw16, 262144);
  cvt_f16<<<256, 256, 0, stream>>>(fc_w, fc16, 65536);
  build_gw<<<2048, 256, 0, stream>>>(g1, g2, gw16);
  trans_attn<<<dim3(8, 8, 4), 256, 0, stream>>>(attn, attnT);

  // --- heavy pipeline (per chunk) ---
  for (int c = 0; c < nchunk; ++c) {
    const int z0 = c * ZCv;
    GP q;
    // Wh = h*W^T + bW  (+ WhT dual store)
    q = GP{};
    q.A = h16; q.B = W16; q.C = WhC; q.bias = bW; q.aux = WhTC;
    q.K = 512; q.ldA = 512; q.ldB = 512; q.ldC = 512; q.z0 = z0;
    q.ntx = 8; q.nty = 2; q.nz = ZCv;
    q.sAz = 0; q.sAb = 524288; q.sBz = 0; q.sBh = 262144;
    q.sCz = 524288; q.sCb = 0; q.sCh = 0; q.sBiasH = 512; q.sAuxZ = 524288;
    gemm_wh<<<16 * ZCv, 512, 0, stream>>>(q);
    // e = Wh*attn
    q = GP{};
    q.A = WhC; q.B = attnT; q.C = eC;
    q.K = 512; q.ldA = 512; q.ldB = 512; q.ldC = 512; q.z0 = z0;
    q.ntx = 8; q.nty = 2; q.nz = ZCv;
    q.sAz = 524288; q.sBh = 262144; q.sCz = 524288;
    gemm_e<<<16 * ZCv, 512, 0, stream>>>(q);
    // Amat = tanh(mask(e*Wh^T))
    q = GP{};
    q.A = eC; q.B = WhC; q.C = AmatC; q.adjb = adjb;
    q.K = 512; q.ldA = 512; q.ldB = 512; q.ldC = 1024; q.z0 = z0;
    q.ntx = 8; q.nty = 4; q.nz = ZCv;
    q.sAz = 524288; q.sBz = 524288; q.sCz = 1048576;
    gemm_amat<<<32 * ZCv, 512, 0, stream>>>(q);
    // cat[b][n][h*512+o] = relu(Amat*WhT^T)
    q = GP{};
    q.A = AmatC; q.B = WhTC; q.C = cat;
    q.K = 1024; q.ldA = 1024; q.ldB = 1024; q.ldC = 2048; q.z0 = z0;
    q.sAz = 1048576; q.sBz = 524288;
    q.ntx = 8; q.nty = 2; q.nz = ZCv;
    q.sCz = 0; q.sCb = 2097152; q.sCh = 512;
    gemm_cat<<<16 * ZCv, 512, 0, stream>>>(q);
  }

  // --- tail ---
  GP q;
  // hf = h*fc^T -> gcat[:,0:512]
  q = GP{};
  q.A = h16; q.B = fc16; q.C = gcat;
  q.K = 512; q.ldA = 512; q.ldB = 512; q.ldC = 1024; q.z0 = 0;
  q.ntx = 128; q.nty = 2; q.nz = 1;
  gemm_hf<<<256, 512, 0, stream>>>(q);
  // ha = cat*A_w^T -> gcat[:,512:1024]
  q = GP{};
  q.A = cat; q.B = Aw16; q.C = gcat + 512;
  q.K = 2048; q.ldA = 2048; q.ldB = 2048; q.ldC = 1024; q.z0 = 0;
  q.ntx = 128; q.nty = 2; q.nz = 1;
  gemm_ha<<<256, 512, 0, stream>>>(q);
  // coeff = sigmoid(gcat*[g1|g2]^T + gbias)
  q = GP{};
  q.A = gcat; q.B = gw16; q.C = coeff; q.bias = gbias;
  q.K = 1024; q.ldA = 1024; q.ldB = 1024; q.ldC = 512; q.z0 = 0;
  q.ntx = 128; q.nty = 2; q.nz = 1; q.sBiasH = 0;
  gemm_gate<<<256, 512, 0, stream>>>(q);
  // out = hf*cf + ha*(1-cf)
  mix_kernel<<<2048, 256, 0, stream>>>(gcat, coeff, out);
}